// Round 6
// baseline (73.277 us; speedup 1.0000x reference)
//
#include <hip/hip_runtime.h>
#include <hip/hip_bf16.h>
#include <cstdint>

#define LL 256   // L
#define NN 512   // N
#define DD 256   // D
#define HH 8
#define EPSF 1e-5f

typedef __attribute__((ext_vector_type(8))) __bf16 bf16x8;
typedef __attribute__((ext_vector_type(4))) float f32x4;

// ---------------- K0: per-l fused weights Wg = gamma ⊙ (q·Wk), G[h] = Σ_c Wg ----------------
__global__ __launch_bounds__(512) void k_prep(
    const float* __restrict__ msa, const float* __restrict__ Wq,
    const float* __restrict__ bq, const float* __restrict__ Wk,
    const float* __restrict__ gamma, const float* __restrict__ beta,
    unsigned short* __restrict__ Wg, float* __restrict__ Gout)
{
    const int l = blockIdx.x, tid = threadIdx.x;
    const int wave = tid >> 6, lane = tid & 63;
    __shared__ float lnx[DD];
    __shared__ float qv[DD];
    __shared__ float red[8];
    __shared__ float Gpart[HH][4];

    // LN of target row (first 4 waves)
    float x0 = (tid < DD) ? msa[(size_t)l * DD + tid] : 0.f;
    float s = x0, ss = x0 * x0;
    #pragma unroll
    for (int m = 32; m >= 1; m >>= 1) { s += __shfl_xor(s, m); ss += __shfl_xor(ss, m); }
    if (tid < DD && lane == 0) { red[wave * 2] = s; red[wave * 2 + 1] = ss; }
    __syncthreads();
    if (tid < DD) {
        float sm = red[0] + red[2] + red[4] + red[6];
        float sq = red[1] + red[3] + red[5] + red[7];
        float mean = sm * (1.f / DD);
        float var  = sq * (1.f / DD) - mean * mean;
        float rs   = rsqrtf(var + EPSF);
        lnx[tid] = (x0 - mean) * rs * gamma[tid] + beta[tid];
    }
    __syncthreads();

    // q-GEMV, wave-per-row (coalesced Wq reads): wave handles rows wave*32..+31
    {
        f32x4 lx = *(const f32x4*)(lnx + lane * 4);
        #pragma unroll 4
        for (int rr = 0; rr < 32; ++rr) {
            int r = wave * 32 + rr;
            float4 wv = *(const float4*)(Wq + (size_t)r * DD + lane * 4);
            float p = wv.x * lx[0] + wv.y * lx[1] + wv.z * lx[2] + wv.w * lx[3];
            #pragma unroll
            for (int m = 32; m >= 1; m >>= 1) p += __shfl_xor(p, m);
            if (lane == 0) qv[r] = (p + bq[r]) * 0.17677669529663687f;
        }
    }
    __syncthreads();

    // Wg rows: thread -> column c, 4 heads per half
    const int c = tid & 255, h0 = (tid >> 8) * 4;
    const float gm = gamma[c];
    #pragma unroll
    for (int hi = 0; hi < 4; ++hi) {
        int h = h0 + hi;
        float a = 0.f;
        const float* wk = Wk + ((size_t)h * 32) * DD + c;
        #pragma unroll 8
        for (int d = 0; d < 32; ++d)
            a += qv[h * 32 + d] * wk[(size_t)d * DD];
        __bf16 w = (__bf16)(gm * a);
        Wg[((size_t)l * 16 + h) * DD + c] = __builtin_bit_cast(unsigned short, w);
        float gw = (float)w;
        #pragma unroll
        for (int m = 32; m >= 1; m >>= 1) gw += __shfl_xor(gw, m);
        if (lane == 0) Gpart[h][wave & 3] = gw;
    }
    if (tid < DD) {
        Wg[((size_t)l * 16 + 8) * DD + tid] = 0x3F80;   // ones column -> row sums
    } else {
        const int c2 = tid - 256;
        #pragma unroll
        for (int h = 9; h < 16; ++h) Wg[((size_t)l * 16 + h) * DD + c2] = 0;
    }
    __syncthreads();
    if (tid < HH)
        Gout[(size_t)l * HH + tid] = Gpart[tid][0] + Gpart[tid][1] + Gpart[tid][2] + Gpart[tid][3];
}

// ---------------- K1: adjusted logits straight to d_out. 2048 independent blocks ----------------
__global__ __launch_bounds__(256) void k_logits(
    const float* __restrict__ msa, const unsigned short* __restrict__ Wg,
    const float* __restrict__ Gs, float* __restrict__ out)
{
    const int bid = blockIdx.x;
    const int l = bid >> 3, ch = bid & 7;
    const int tid = threadIdx.x, wave = tid >> 6, lane = tid & 63;
    const int col = lane & 15, kb = lane >> 4;

    bf16x8 bfr[8];
    {
        const unsigned short* wp = Wg + ((size_t)l * 16 + col) * DD + kb * 8;
        #pragma unroll
        for (int ks = 0; ks < 8; ++ks)
            bfr[ks] = *(const bf16x8*)(wp + ks * 32);
    }
    const float Gh = Gs[(size_t)l * HH + (col & 7)];

    const int n0 = ch * 64 + wave * 16;
    const float* rp = msa + ((size_t)(n0 + col) * LL + l) * DD + (kb << 3);
    f32x4 hacc = {0.f, 0.f, 0.f, 0.f}, gacc = {0.f, 0.f, 0.f, 0.f};
    #pragma unroll
    for (int half = 0; half < 2; ++half) {
        float4 u[4], v[4];
        #pragma unroll
        for (int j = 0; j < 4; ++j) {
            u[j] = *(const float4*)(rp + (half * 4 + j) * 32);
            v[j] = *(const float4*)(rp + (half * 4 + j) * 32 + 4);
        }
        #pragma unroll
        for (int j = 0; j < 4; ++j) {
            bf16x8 a;
            a[0] = (__bf16)u[j].x; a[1] = (__bf16)u[j].y; a[2] = (__bf16)u[j].z; a[3] = (__bf16)u[j].w;
            a[4] = (__bf16)v[j].x; a[5] = (__bf16)v[j].y; a[6] = (__bf16)v[j].z; a[7] = (__bf16)v[j].w;
            hacc = __builtin_amdgcn_mfma_f32_16x16x32_bf16(a, bfr[half * 4 + j], hacc, 0, 0, 0);
            gacc = __builtin_amdgcn_mfma_f32_16x16x32_bf16(a, a,                 gacc, 0, 0, 0);
        }
    }
    // Row stats via in-wave exchange: sS from ones-column lane (kb*16+8, elem i),
    // sQ from Gram-diagonal lane (kb*20+i, elem i). C/D: col=lane&15, row=kb*4+i.
    #pragma unroll
    for (int i = 0; i < 4; ++i) {
        float sSv = __shfl(hacc[i], kb * 16 + 8);
        float sQv = __shfl(gacc[i], kb * 20 + i);
        float mean = sSv * (1.f / DD);
        float var  = sQv * (1.f / DD) - mean * mean;
        float rs   = rsqrtf(var + EPSF);
        float adj  = rs * (hacc[i] - mean * Gh);
        int n = n0 + (kb << 2) + i;
        if (col < HH)
            out[(size_t)n * (LL * HH) + (size_t)l * HH + col] = adj;
    }
}

// ---------------- K2: in-place softmax over n for each (l, h) ----------------
__global__ __launch_bounds__(512) void k_soft(float* __restrict__ out)
{
    const int l = blockIdx.x, n = threadIdx.x;
    const int wave = n >> 6, lane = n & 63;
    __shared__ float red[HH][8];

    float* p = out + (size_t)n * (LL * HH) + (size_t)l * HH;
    float4 a = *(const float4*)p, b = *(const float4*)(p + 4);
    float v[8] = {a.x, a.y, a.z, a.w, b.x, b.y, b.z, b.w};

    // per-head max over n
    #pragma unroll
    for (int h = 0; h < HH; ++h) {
        float m = v[h];
        #pragma unroll
        for (int s = 32; s >= 1; s >>= 1) m = fmaxf(m, __shfl_xor(m, s));
        if (lane == 0) red[h][wave] = m;
    }
    __syncthreads();
    float mh[8];
    #pragma unroll
    for (int h = 0; h < HH; ++h) {
        float m = red[h][0];
        #pragma unroll
        for (int w = 1; w < 8; ++w) m = fmaxf(m, red[h][w]);
        mh[h] = m;
    }
    __syncthreads();
    // per-head sum of exp
    float e[8];
    #pragma unroll
    for (int h = 0; h < HH; ++h) {
        e[h] = __expf(v[h] - mh[h]);
        float s = e[h];
        #pragma unroll
        for (int m = 32; m >= 1; m >>= 1) s += __shfl_xor(s, m);
        if (lane == 0) red[h][wave] = s;
    }
    __syncthreads();
    #pragma unroll
    for (int h = 0; h < HH; ++h) {
        float s = red[h][0] + red[h][1] + red[h][2] + red[h][3]
                + red[h][4] + red[h][5] + red[h][6] + red[h][7];
        e[h] *= (1.f / s);
    }
    float4 p0 = {e[0], e[1], e[2], e[3]};
    float4 p1 = {e[4], e[5], e[6], e[7]};
    *(float4*)(p)     = p0;
    *(float4*)(p + 4) = p1;
}

extern "C" void kernel_launch(void* const* d_in, const int* in_sizes, int n_in,
                              void* d_out, int out_size, void* d_ws, size_t ws_size,
                              hipStream_t stream) {
    (void)in_sizes; (void)n_in; (void)out_size; (void)ws_size;
    const float* msa   = (const float*)d_in[0];
    const float* Wq    = (const float*)d_in[1];
    const float* bq    = (const float*)d_in[2];
    const float* Wk    = (const float*)d_in[3];
    // d_in[4] = bk: per-(l,h) constant in logits -> cancelled by softmax over n.
    const float* gamma = (const float*)d_in[5];
    const float* beta  = (const float*)d_in[6];
    unsigned short* Wg = (unsigned short*)d_ws;                      // [256][16][256] bf16 = 2 MB
    float* Gs = (float*)((char*)d_ws + (size_t)2 * 1024 * 1024);     // [256][8] f32
    float* out = (float*)d_out;
    k_prep  <<<dim3(LL),     dim3(512), 0, stream>>>(msa, Wq, bq, Wk, gamma, beta, Wg, Gs);
    k_logits<<<dim3(LL * 8), dim3(256), 0, stream>>>(msa, Wg, Gs, out);
    k_soft  <<<dim3(LL),     dim3(512), 0, stream>>>(out);
}

// Round 7
// 42.926 us; speedup vs baseline: 1.7071x; 1.7071x over previous
//
#include <hip/hip_runtime.h>
#include <hip/hip_bf16.h>
#include <cstdint>

#define LL 256   // L
#define NN 512   // N
#define DD 256   // D
#define HH 8
#define EPSF 1e-5f
#define WGS 264  // padded LDS row stride (bf16 elems) for Wg

typedef __attribute__((ext_vector_type(8))) __bf16 bf16x8;
typedef __attribute__((ext_vector_type(4))) float f32x4;

static __device__ __forceinline__ void load_group(
    const float* __restrict__ msa, int l, int wave, int col, int kb, int g,
    float4 (&buf)[16])
{
    const float* rp = msa + ((size_t)(g * 128 + (wave << 4) + col) * LL + l) * DD + (kb << 3);
    #pragma unroll
    for (int ks = 0; ks < 8; ++ks) {
        buf[2 * ks]     = *(const float4*)(rp + ks * 32);
        buf[2 * ks + 1] = *(const float4*)(rp + ks * 32 + 4);
    }
}

static __device__ __forceinline__ void compute_group(
    const float4 (&buf)[16], const bf16x8 (&bfr)[8], f32x4& hacc, f32x4& gacc)
{
    #pragma unroll
    for (int ks = 0; ks < 8; ++ks) {
        float4 u = buf[2 * ks], v = buf[2 * ks + 1];
        bf16x8 a;
        a[0] = (__bf16)u.x; a[1] = (__bf16)u.y; a[2] = (__bf16)u.z; a[3] = (__bf16)u.w;
        a[4] = (__bf16)v.x; a[5] = (__bf16)v.y; a[6] = (__bf16)v.z; a[7] = (__bf16)v.w;
        hacc = __builtin_amdgcn_mfma_f32_16x16x32_bf16(a, bfr[ks], hacc, 0, 0, 0);
        gacc = __builtin_amdgcn_mfma_f32_16x16x32_bf16(a, a,       gacc, 0, 0, 0);
    }
}

static __device__ __forceinline__ void store_group(
    int g, int wave, int col, int kb, const f32x4& hacc, const f32x4& gacc,
    float* logits, float* sS, float* sQ)
{
    const int nb = g * 128 + (wave << 4);
    #pragma unroll
    for (int i = 0; i < 4; ++i) {
        int n = nb + (kb << 2) + i;          // C/D: col=lane&15, row=kb*4+i
        if (col < HH)       logits[col * NN + n] = hacc[i];
        else if (col == HH) sS[n] = hacc[i];
    }
    if (kb == (col >> 2)) sQ[nb + col] = gacc[col & 3];   // Gram diagonal
}

__global__
__attribute__((amdgpu_flat_work_group_size(512, 512), amdgpu_waves_per_eu(2, 2)))
void k_fused(
    const float* __restrict__ msa, const float* __restrict__ Wq,
    const float* __restrict__ bq, const float* __restrict__ Wk,
    const float* __restrict__ gamma, const float* __restrict__ beta,
    float* __restrict__ out)
{
    const int l = blockIdx.x;
    const int tid = threadIdx.x, wave = tid >> 6, lane = tid & 63;
    const int col = lane & 15, kb = lane >> 4;

    __shared__ __align__(16) float logits[HH * NN];   // 16 KB
    __shared__ __align__(16) float sS[NN];            // 2 KB   Σx̂ per row
    __shared__ __align__(16) float sQ[NN];            // 2 KB   Σx̂² per row
    __shared__ __align__(16) __bf16 WgL[16 * WGS];    // 8.25 KB
    __shared__ float lnx[DD];
    __shared__ float qv[DD];
    __shared__ float red[8];
    __shared__ float stats[16];
    __shared__ float Gs[HH];

    // ---- prefetch tiles 0 and 1 NOW; with waves_per_eu(2,2) these stay VGPR-resident ----
    float4 A[16], B[16];
    load_group(msa, l, wave, col, kb, 0, A);
    load_group(msa, l, wave, col, kb, 1, B);

    // ---------- Phase 1: Wg = gamma ⊙ (q·Wk) in LDS ----------
    {
        float x0 = (tid < DD) ? msa[(size_t)l * DD + tid] : 0.f;
        float s = x0, ss = x0 * x0;
        #pragma unroll
        for (int m = 32; m >= 1; m >>= 1) { s += __shfl_xor(s, m); ss += __shfl_xor(ss, m); }
        if (tid < DD && lane == 0) { red[wave * 2] = s; red[wave * 2 + 1] = ss; }
        __syncthreads();
        if (tid < DD) {
            float sm = red[0] + red[2] + red[4] + red[6];
            float sq = red[1] + red[3] + red[5] + red[7];
            float mean = sm * (1.f / DD);
            float var  = sq * (1.f / DD) - mean * mean;
            float rs   = rsqrtf(var + EPSF);
            lnx[tid] = (x0 - mean) * rs * gamma[tid] + beta[tid];
        }
        __syncthreads();
        // q = (Wq · lnx + bq) * 1/sqrt(DH); each row split across 2 threads
        const int r = tid & 255, hf = tid >> 8;
        float acc = 0.f;
        {
            const float4* wr = (const float4*)(Wq + (size_t)r * DD) + hf * 32;
            const float* lx = lnx + hf * 128;
            #pragma unroll 4
            for (int j = 0; j < 32; ++j) {
                float4 w4 = wr[j];
                acc += lx[4*j] * w4.x + lx[4*j+1] * w4.y + lx[4*j+2] * w4.z + lx[4*j+3] * w4.w;
            }
        }
        if (hf == 0) qv[r] = acc;
        __syncthreads();
        if (hf == 1) qv[r] = (qv[r] + acc + bq[r]) * 0.17677669529663687f;
        __syncthreads();
        // Wg rows: thread handles col c for 4 heads (half-split by tid>>8)
        const int c = tid & 255, h0 = (tid >> 8) * 4;
        const float gm = gamma[c];
        #pragma unroll
        for (int hi = 0; hi < 4; ++hi) {
            int h = h0 + hi;
            float a = 0.f;
            const float* wk = Wk + ((size_t)h * 32) * DD + c;
            #pragma unroll 8
            for (int d = 0; d < 32; ++d)
                a += qv[h * 32 + d] * wk[(size_t)d * DD];
            WgL[h * WGS + c] = (__bf16)(gm * a);
        }
        if (tid < DD) {
            WgL[8 * WGS + tid] = (__bf16)1.0f;     // ones column -> row sums
        } else {
            const int c2 = tid - 256;
            #pragma unroll
            for (int h = 9; h < 16; ++h) WgL[h * WGS + c2] = (__bf16)0.0f;
        }
        __syncthreads();
        if (wave < HH) {                           // G[h] = sum_c Wg[h][c]
            float gsum = 0.f;
            #pragma unroll
            for (int i = 0; i < 4; ++i) gsum += (float)WgL[wave * WGS + lane * 4 + i];
            #pragma unroll
            for (int m = 32; m >= 1; m >>= 1) gsum += __shfl_xor(gsum, m);
            if (lane == 0) Gs[wave] = gsum;
        }
        __syncthreads();
    }

    // ---------- B fragments from LDS ----------
    bf16x8 bfr[8];
    #pragma unroll
    for (int ks = 0; ks < 8; ++ks)
        bfr[ks] = *(const bf16x8*)&WgL[col * WGS + ks * 32 + kb * 8];

    // ---------- Main loop: 4 groups of 16 rows/wave, 2-deep pipelined ----------
    const f32x4 z = {0.f, 0.f, 0.f, 0.f};
    {
        f32x4 ha = z, ga = z;
        compute_group(A, bfr, ha, ga);
        load_group(msa, l, wave, col, kb, 2, A);
        store_group(0, wave, col, kb, ha, ga, logits, sS, sQ);
    }
    {
        f32x4 ha = z, ga = z;
        compute_group(B, bfr, ha, ga);
        load_group(msa, l, wave, col, kb, 3, B);
        store_group(1, wave, col, kb, ha, ga, logits, sS, sQ);
    }
    {
        f32x4 ha = z, ga = z;
        compute_group(A, bfr, ha, ga);
        store_group(2, wave, col, kb, ha, ga, logits, sS, sQ);
    }
    {
        f32x4 ha = z, ga = z;
        compute_group(B, bfr, ha, ga);
        store_group(3, wave, col, kb, ha, ga, logits, sS, sQ);
    }
    __syncthreads();

    // ---------- softmax stats: wave w -> head h=w ----------
    {
        const int h = wave;
        const float Gh = Gs[h];
        const float* lp = logits + h * NN;
        float4 ra = ((const float4*)lp)[lane * 2];
        float4 rb = ((const float4*)lp)[lane * 2 + 1];
        float4 sa = ((const float4*)sS)[lane * 2];
        float4 sb = ((const float4*)sS)[lane * 2 + 1];
        float4 qa = ((const float4*)sQ)[lane * 2];
        float4 qb = ((const float4*)sQ)[lane * 2 + 1];
        float raw[8] = {ra.x, ra.y, ra.z, ra.w, rb.x, rb.y, rb.z, rb.w};
        float sv[8]  = {sa.x, sa.y, sa.z, sa.w, sb.x, sb.y, sb.z, sb.w};
        float qv2[8] = {qa.x, qa.y, qa.z, qa.w, qb.x, qb.y, qb.z, qb.w};
        float adj[8];
        #pragma unroll
        for (int i = 0; i < 8; ++i) {
            float mean = sv[i] * (1.f / DD);
            float var  = qv2[i] * (1.f / DD) - mean * mean;
            float rs   = rsqrtf(var + EPSF);
            adj[i] = rs * (raw[i] - mean * Gh);
        }
        float mx = adj[0];
        #pragma unroll
        for (int i = 1; i < 8; ++i) mx = fmaxf(mx, adj[i]);
        #pragma unroll
        for (int m = 32; m >= 1; m >>= 1) mx = fmaxf(mx, __shfl_xor(mx, m));
        float sm = 0.f;
        #pragma unroll
        for (int i = 0; i < 8; ++i) sm += __expf(adj[i] - mx);
        #pragma unroll
        for (int m = 32; m >= 1; m >>= 1) sm += __shfl_xor(sm, m);
        if (lane == 0) { stats[wave] = mx; stats[8 + wave] = 1.f / sm; }
    }
    __syncthreads();

    // ---------- epilogue: thread t -> n=t, 8 heads, fp32 out ----------
    {
        const int n = tid;
        float s = sS[n], q2 = sQ[n];
        float mean = s * (1.f / DD);
        float var  = q2 * (1.f / DD) - mean * mean;
        float rs   = rsqrtf(var + EPSF);
        float o[8];
        #pragma unroll
        for (int h = 0; h < HH; ++h) {
            float adj = rs * (logits[h * NN + n] - mean * Gs[h]);
            o[h] = __expf(adj - stats[h]) * stats[8 + h];
        }
        float* op = out + (size_t)n * LL * HH + (size_t)l * HH;
        float4 p0 = {o[0], o[1], o[2], o[3]};
        float4 p1 = {o[4], o[5], o[6], o[7]};
        *(float4*)(op)     = p0;
        *(float4*)(op + 4) = p1;
    }
}

extern "C" void kernel_launch(void* const* d_in, const int* in_sizes, int n_in,
                              void* d_out, int out_size, void* d_ws, size_t ws_size,
                              hipStream_t stream) {
    (void)in_sizes; (void)n_in; (void)out_size; (void)d_ws; (void)ws_size;
    const float* msa   = (const float*)d_in[0];
    const float* Wq    = (const float*)d_in[1];
    const float* bq    = (const float*)d_in[2];
    const float* Wk    = (const float*)d_in[3];
    // d_in[4] = bk: per-(l,h) constant in logits -> cancelled by softmax over n.
    const float* gamma = (const float*)d_in[5];
    const float* beta  = (const float*)d_in[6];
    k_fused<<<dim3(LL), dim3(512), 0, stream>>>(msa, Wq, bq, Wk, gamma, beta, (float*)d_out);
}